// Round 11
// baseline (218.478 us; speedup 1.0000x reference)
//
#include <hip/hip_runtime.h>
#include <hip/hip_bf16.h>
#include <cstdint>

#define B_ROWS 4096
#define DIM 1024
#define NN 8192  // 2*B

typedef float f32x4 __attribute__((ext_vector_type(4)));
typedef long lx2 __attribute__((ext_vector_type(2)));

__device__ __forceinline__ float wave_reduce_sum(float v) {
    v += __shfl_xor(v, 1);
    v += __shfl_xor(v, 2);
    v += __shfl_xor(v, 4);
    v += __shfl_xor(v, 8);
    v += __shfl_xor(v, 16);
    v += __shfl_xor(v, 32);
    return v;
}

// fp32 -> OCP e4m3fn, round-to-nearest-even. Inputs here satisfy |x| < 0.5,
// so no overflow/NaN handling needed. Subnormal cutoff at 2^-6.
__device__ __forceinline__ unsigned char f32_to_e4m3(float x) {
    unsigned int b = __float_as_uint(x);
    unsigned int sign = (b >> 24) & 0x80u;
    unsigned int ab = b & 0x7FFFFFFFu;
    unsigned int out;
    if (__uint_as_float(ab) >= 0.015625f) {
        unsigned int rb = ab + 0x7FFFFu + ((ab >> 20) & 1u);  // RNE at 3 mantissa bits
        int E = (int)(rb >> 23) - 127;
        out = (unsigned int)((E + 7) << 3) | ((rb >> 20) & 7u);
    } else {
        out = (unsigned int)rintf(__uint_as_float(ab) * 512.0f);  // subnormal, 0..8
    }
    return (unsigned char)(out | sign);
}

// Kernel 1: L2-normalize + positives, ONE WAVE PER ROW-PAIR (i of p1, i of p2).
// No LDS, no barriers. Lane l covers float4s {l, l+64, l+128, l+192} of each row.
__global__ void norm_pos_kernel(const float* __restrict__ p1,
                                const float* __restrict__ p2,
                                unsigned char* __restrict__ rep,
                                float* __restrict__ pos) {
    const int wv = threadIdx.x >> 6, lane = threadIdx.x & 63;
    const int i = blockIdx.x * 4 + wv;  // 0..4095
    const float4* ap = (const float4*)(p1 + (size_t)i * DIM);
    const float4* bp = (const float4*)(p2 + (size_t)i * DIM);
    float4 a[4], b[4];
#pragma unroll
    for (int c = 0; c < 4; ++c) { a[c] = ap[lane + 64 * c]; b[c] = bp[lane + 64 * c]; }
    float s1 = 0.f, s2 = 0.f, dp = 0.f;
#pragma unroll
    for (int c = 0; c < 4; ++c) {
        s1 += a[c].x * a[c].x + a[c].y * a[c].y + a[c].z * a[c].z + a[c].w * a[c].w;
        s2 += b[c].x * b[c].x + b[c].y * b[c].y + b[c].z * b[c].z + b[c].w * b[c].w;
        dp += a[c].x * b[c].x + a[c].y * b[c].y + a[c].z * b[c].z + a[c].w * b[c].w;
    }
    s1 = wave_reduce_sum(s1);
    s2 = wave_reduce_sum(s2);
    dp = wave_reduce_sum(dp);
    const float sc1 = rsqrtf(s1), sc2 = rsqrtf(s2);
    uchar4* o1 = (uchar4*)(rep + (size_t)i * DIM);
    uchar4* o2 = (uchar4*)(rep + (size_t)(i + B_ROWS) * DIM);
#pragma unroll
    for (int c = 0; c < 4; ++c) {
        uchar4 u1, u2;
        u1.x = f32_to_e4m3(a[c].x * sc1); u1.y = f32_to_e4m3(a[c].y * sc1);
        u1.z = f32_to_e4m3(a[c].z * sc1); u1.w = f32_to_e4m3(a[c].w * sc1);
        u2.x = f32_to_e4m3(b[c].x * sc2); u2.y = f32_to_e4m3(b[c].y * sc2);
        u2.z = f32_to_e4m3(b[c].z * sc2); u2.w = f32_to_e4m3(b[c].w * sc2);
        o1[lane + 64 * c] = u1;
        o2[lane + 64 * c] = u2;
    }
    if (lane == 0) pos[i] = dp * sc1 * sc2;
}

// Kernel 2: symmetric fused GEMM in fp8 e4m3, upper-triangle tiles (rb<=cb),
// BK=64, 2x2 waves (64x64 each, 4x4 frags of 16x16x32).
//
// NO LDS, NO BARRIERS: each lane's fragment is 16 CONTIGUOUS bytes of rep
// (row-major, K innermost): rep[row*1024 + kk*64 + q*16] — loaded directly
// global->VGPR as global_load_dwordx4. Per wave-instruction the 64 lanes
// touch 16 fully-used 64B lines (same line efficiency as a float4 stream).
// Register double-buffer: issue tile kk+1's 8 loads, then MFMA tile kk —
// with no barrier in the loop the compiler emits fine-grained
// s_waitcnt vmcnt(N>0), the hipBLASLt/AITER pattern. A-halves are read by
// 2 waves (wc pair) and B-halves by 2 (wr pair): second reader hits L1.
//
// K-permutation trick (R7, proven): the 16B slot's low 8B feed MFMA h=0 and
// high 8B h=1; A and B lanes with equal q carry the same global k-range, so
// the contraction is consistent (any k-bijection applied to both operands
// is invariant).
__global__ __launch_bounds__(256) void gemm_kernel(const unsigned char* __restrict__ rep,
                                                   float* __restrict__ partial) {
    // rb-major triangle decode: start(rb) = 64*rb - rb*(rb-1)/2
    const int bid = blockIdx.x;
    int rb = (int)(64.5f - sqrtf(4160.25f - 2.0f * (float)bid));
    while (64 * (rb + 1) - (rb + 1) * rb / 2 <= bid) ++rb;
    while (64 * rb - rb * (rb - 1) / 2 > bid) --rb;
    const int cb = rb + (bid - (64 * rb - rb * (rb - 1) / 2));

    const int t = threadIdx.x;
    const int lane = t & 63;
    const int wv = t >> 6;     // 0..3
    const int wr = wv >> 1;    // wave row-half
    const int wc = wv & 1;     // wave col-half
    const int cm = lane & 15;  // frag m,n index
    const int q = lane >> 4;   // frag k-quarter

    // per-lane fragment stream pointers (k-invariant bases)
    const unsigned char* aP[4];
    const unsigned char* bP[4];
#pragma unroll
    for (int mi = 0; mi < 4; ++mi)
        aP[mi] = rep + (size_t)(rb * 128 + wr * 64 + mi * 16 + cm) * DIM + q * 16;
#pragma unroll
    for (int ni = 0; ni < 4; ++ni)
        bP[ni] = rep + (size_t)(cb * 128 + wc * 64 + ni * 16 + cm) * DIM + q * 16;

    f32x4 acc[4][4];
#pragma unroll
    for (int i = 0; i < 4; ++i)
#pragma unroll
        for (int j = 0; j < 4; ++j) acc[i][j] = (f32x4){0.f, 0.f, 0.f, 0.f};

    lx2 aA[4], bA[4], aB[4], bB[4];
    // prologue: tile 0 -> buffer A
#pragma unroll
    for (int mi = 0; mi < 4; ++mi) aA[mi] = *(const lx2*)(aP[mi]);
#pragma unroll
    for (int ni = 0; ni < 4; ++ni) bA[ni] = *(const lx2*)(bP[ni]);

    for (int kk = 0; kk < DIM / 64; kk += 2) {
        // issue tile kk+1 -> buffer B
#pragma unroll
        for (int mi = 0; mi < 4; ++mi) aB[mi] = *(const lx2*)(aP[mi] + 64);
#pragma unroll
        for (int ni = 0; ni < 4; ++ni) bB[ni] = *(const lx2*)(bP[ni] + 64);
        // compute tile kk from buffer A
#pragma unroll
        for (int h = 0; h < 2; ++h)
#pragma unroll
            for (int mi = 0; mi < 4; ++mi)
#pragma unroll
                for (int ni = 0; ni < 4; ++ni)
                    acc[mi][ni] = __builtin_amdgcn_mfma_f32_16x16x32_fp8_fp8(
                        aA[mi][h], bA[ni][h], acc[mi][ni], 0, 0, 0);
        // issue tile kk+2 -> buffer A
        if (kk + 2 < DIM / 64) {
#pragma unroll
            for (int mi = 0; mi < 4; ++mi) aA[mi] = *(const lx2*)(aP[mi] + 128);
#pragma unroll
            for (int ni = 0; ni < 4; ++ni) bA[ni] = *(const lx2*)(bP[ni] + 128);
        }
        // compute tile kk+1 from buffer B
#pragma unroll
        for (int h = 0; h < 2; ++h)
#pragma unroll
            for (int mi = 0; mi < 4; ++mi)
#pragma unroll
                for (int ni = 0; ni < 4; ++ni)
                    acc[mi][ni] = __builtin_amdgcn_mfma_f32_16x16x32_fp8_fp8(
                        aB[mi][h], bB[ni][h], acc[mi][ni], 0, 0, 0);
#pragma unroll
        for (int mi = 0; mi < 4; ++mi) aP[mi] += 128;
#pragma unroll
        for (int ni = 0; ni < 4; ++ni) bP[ni] += 128;
    }

    // Epilogue. C/D layout: col = wc*64 + ni*16 + cm, row = wr*64 + mi*16 + q*4 + reg.
    // Row-partials -> slot 2*cb+wc; transpose col-partials -> slot 2*rb+wr.
    // Row r of block i receives slots {2c,2c+1 : c>=i} ∪ {2c,2c+1 : c<i} = all 128, disjoint.
    float colsum[4];
#pragma unroll
    for (int ni = 0; ni < 4; ++ni) colsum[ni] = 0.f;

#pragma unroll
    for (int mi = 0; mi < 4; ++mi) {
#pragma unroll
        for (int reg = 0; reg < 4; ++reg) {
            const int grow = rb * 128 + wr * 64 + mi * 16 + (q << 2) + reg;
            float rs = 0.f;
#pragma unroll
            for (int ni = 0; ni < 4; ++ni) {
                const int gcol = cb * 128 + wc * 64 + ni * 16 + cm;
                const float e =
                    (grow == gcol) ? 0.f : __expf(acc[mi][ni][reg] * 2.0f);  // 1/T=2
                rs += e;
                colsum[ni] += e;
            }
            rs += __shfl_xor(rs, 1);
            rs += __shfl_xor(rs, 2);
            rs += __shfl_xor(rs, 4);
            rs += __shfl_xor(rs, 8);
            if (cm == 0) partial[(size_t)(2 * cb + wc) * NN + grow] = rs;
        }
    }

    if (rb != cb) {
#pragma unroll
        for (int ni = 0; ni < 4; ++ni) {
            colsum[ni] += __shfl_xor(colsum[ni], 16);  // fold q
            colsum[ni] += __shfl_xor(colsum[ni], 32);
        }
        if (q == 0) {
#pragma unroll
            for (int ni = 0; ni < 4; ++ni)
                partial[(size_t)(2 * rb + wr) * NN + cb * 128 + wc * 64 + ni * 16 + cm] =
                    colsum[ni];
        }
    }
}

// Kernel 3: per-row denom -> per-row loss -> 64 block sums. 2 threads/row
// (each 64 of the 128 slots, folded by shfl_xor(1)).
__global__ void reduce_rows_kernel(const float* __restrict__ partial,
                                   const float* __restrict__ pos,
                                   float* __restrict__ bsum) {
    const int g = blockIdx.x * 256 + threadIdx.x;  // 64 x 256 = 16384
    const int r = g >> 1;
    const int half = g & 1;
    float s0 = 0.f, s1 = 0.f, s2 = 0.f, s3 = 0.f;
    for (int kb = half * 64; kb < half * 64 + 64; kb += 4) {
        s0 += partial[(size_t)(kb + 0) * NN + r];
        s1 += partial[(size_t)(kb + 1) * NN + r];
        s2 += partial[(size_t)(kb + 2) * NN + r];
        s3 += partial[(size_t)(kb + 3) * NN + r];
    }
    float s = (s0 + s1) + (s2 + s3);
    s += __shfl_xor(s, 1);  // both lanes of the pair now hold the full row sum
    float v = __logf(s) - pos[r & (B_ROWS - 1)] * 2.0f;  // counted twice; /2 below
    v = wave_reduce_sum(v);
    __shared__ float red[4];
    const int lane = threadIdx.x & 63, wv = threadIdx.x >> 6;
    if (lane == 0) red[wv] = v;
    __syncthreads();
    if (threadIdx.x == 0)
        bsum[blockIdx.x] = (red[0] + red[1] + red[2] + red[3]) * 0.5f;
}

// Kernel 4: final scalar
__global__ void final_kernel(const float* __restrict__ bsum,
                             float* __restrict__ out) {
    float s = bsum[threadIdx.x];
    s = wave_reduce_sum(s);
    if (threadIdx.x == 0) out[0] = s * (1.0f / NN);
}

extern "C" void kernel_launch(void* const* d_in, const int* in_sizes, int n_in,
                              void* d_out, int out_size, void* d_ws, size_t ws_size,
                              hipStream_t stream) {
    const float* p1 = (const float*)d_in[0];
    const float* p2 = (const float*)d_in[1];
    char* ws = (char*)d_ws;
    unsigned char* rep = (unsigned char*)ws;                  // 8 MiB (fp8)
    float* partial = (float*)(ws + (size_t)8 * 1024 * 1024);  // 4 MiB (128 x 8192)
    float* pos = (float*)(ws + (size_t)12 * 1024 * 1024);     // 16 KiB
    float* bsum = (float*)(ws + (size_t)12 * 1024 * 1024 + 16384);  // 256 B
    float* out = (float*)d_out;

    norm_pos_kernel<<<1024, 256, 0, stream>>>(p1, p2, rep, pos);
    gemm_kernel<<<2080, 256, 0, stream>>>(rep, partial);
    reduce_rows_kernel<<<64, 256, 0, stream>>>(partial, pos, bsum);
    final_kernel<<<1, 64, 0, stream>>>(bsum, out);
}

// Round 12
// 140.962 us; speedup vs baseline: 1.5499x; 1.5499x over previous
//
#include <hip/hip_runtime.h>
#include <hip/hip_bf16.h>
#include <cstdint>

#define B_ROWS 4096
#define DIM 1024
#define NN 8192  // 2*B

typedef float f32x4 __attribute__((ext_vector_type(4)));
typedef long lx2 __attribute__((ext_vector_type(2)));

__device__ __forceinline__ float wave_reduce_sum(float v) {
    v += __shfl_xor(v, 1);
    v += __shfl_xor(v, 2);
    v += __shfl_xor(v, 4);
    v += __shfl_xor(v, 8);
    v += __shfl_xor(v, 16);
    v += __shfl_xor(v, 32);
    return v;
}

__device__ __forceinline__ void gld_lds16(const void* g, void* l) {
    __builtin_amdgcn_global_load_lds(
        (__attribute__((address_space(1))) void*)(uintptr_t)g,
        (__attribute__((address_space(3))) void*)l, 16, 0, 0);
}

// fp32 -> OCP e4m3fn, round-to-nearest-even. Inputs here satisfy |x| < 0.5,
// so no overflow/NaN handling needed. Subnormal cutoff at 2^-6.
__device__ __forceinline__ unsigned char f32_to_e4m3(float x) {
    unsigned int b = __float_as_uint(x);
    unsigned int sign = (b >> 24) & 0x80u;
    unsigned int ab = b & 0x7FFFFFFFu;
    unsigned int out;
    if (__uint_as_float(ab) >= 0.015625f) {
        unsigned int rb = ab + 0x7FFFFu + ((ab >> 20) & 1u);  // RNE at 3 mantissa bits
        int E = (int)(rb >> 23) - 127;
        out = (unsigned int)((E + 7) << 3) | ((rb >> 20) & 7u);
    } else {
        out = (unsigned int)rintf(__uint_as_float(ab) * 512.0f);  // subnormal, 0..8
    }
    return (unsigned char)(out | sign);
}

// Kernel 1: L2-normalize + positives, ONE WAVE PER ROW-PAIR (i of p1, i of p2).
// No LDS, no barriers.
__global__ void norm_pos_kernel(const float* __restrict__ p1,
                                const float* __restrict__ p2,
                                unsigned char* __restrict__ rep,
                                float* __restrict__ pos) {
    const int wv = threadIdx.x >> 6, lane = threadIdx.x & 63;
    const int i = blockIdx.x * 4 + wv;  // 0..4095
    const float4* ap = (const float4*)(p1 + (size_t)i * DIM);
    const float4* bp = (const float4*)(p2 + (size_t)i * DIM);
    float4 a[4], b[4];
#pragma unroll
    for (int c = 0; c < 4; ++c) { a[c] = ap[lane + 64 * c]; b[c] = bp[lane + 64 * c]; }
    float s1 = 0.f, s2 = 0.f, dp = 0.f;
#pragma unroll
    for (int c = 0; c < 4; ++c) {
        s1 += a[c].x * a[c].x + a[c].y * a[c].y + a[c].z * a[c].z + a[c].w * a[c].w;
        s2 += b[c].x * b[c].x + b[c].y * b[c].y + b[c].z * b[c].z + b[c].w * b[c].w;
        dp += a[c].x * b[c].x + a[c].y * b[c].y + a[c].z * b[c].z + a[c].w * b[c].w;
    }
    s1 = wave_reduce_sum(s1);
    s2 = wave_reduce_sum(s2);
    dp = wave_reduce_sum(dp);
    const float sc1 = rsqrtf(s1), sc2 = rsqrtf(s2);
    uchar4* o1 = (uchar4*)(rep + (size_t)i * DIM);
    uchar4* o2 = (uchar4*)(rep + (size_t)(i + B_ROWS) * DIM);
#pragma unroll
    for (int c = 0; c < 4; ++c) {
        uchar4 u1, u2;
        u1.x = f32_to_e4m3(a[c].x * sc1); u1.y = f32_to_e4m3(a[c].y * sc1);
        u1.z = f32_to_e4m3(a[c].z * sc1); u1.w = f32_to_e4m3(a[c].w * sc1);
        u2.x = f32_to_e4m3(b[c].x * sc2); u2.y = f32_to_e4m3(b[c].y * sc2);
        u2.z = f32_to_e4m3(b[c].z * sc2); u2.w = f32_to_e4m3(b[c].w * sc2);
        o1[lane + 64 * c] = u1;
        o2[lane + 64 * c] = u2;
    }
    if (lane == 0) pos[i] = dp * sc1 * sc2;
}

// Kernel 2: symmetric fused GEMM in fp8 e4m3, upper-triangle tiles (rb<=cb),
// BK=64, 2x2 waves (64x64 each, 4x4 frags of 16x16x32). EXACTLY the R7
// structure (best measured: 64.7 us) plus __launch_bounds__(256, 3):
// VGPR 80 + AGPR 64 = ~144/wave -> 3 waves/SIMD fit (432 <= 512); the third
// resident block per CU fills the barrier-drain windows that the measured
// 74k-cyc/CU serialization gap (155k measured vs 81k MFMA + 50k LDS demand)
// consists of. LDS 16 KB/block is not binding.
//
// K-permutation trick: within BK=64 any k-bijection applied to both
// operands is contraction-invariant; each lane ds_read_b128's its swizzled
// 16 B slot once; low 8 B -> MFMA 0, high 8 B -> MFMA 1.
// Staging: thread t -> row t>>2, global 16B seg (t&3)^((row>>1)&3):
// per-quad one 64 B run (coalesced); LDS slot forced to t*16.
__global__ __launch_bounds__(256, 3) void gemm_kernel(const unsigned char* __restrict__ rep,
                                                      float* __restrict__ partial) {
    // rb-major triangle decode: start(rb) = 64*rb - rb*(rb-1)/2
    const int bid = blockIdx.x;
    int rb = (int)(64.5f - sqrtf(4160.25f - 2.0f * (float)bid));
    while (64 * (rb + 1) - (rb + 1) * rb / 2 <= bid) ++rb;
    while (64 * rb - rb * (rb - 1) / 2 > bid) --rb;
    const int cb = rb + (bid - (64 * rb - rb * (rb - 1) / 2));

    __shared__ __align__(16) unsigned char As[8192];  // 8 KB
    __shared__ __align__(16) unsigned char Bs[8192];  // 8 KB
    const int t = threadIdx.x;
    const int lane = t & 63;
    const int wv = t >> 6;     // 0..3
    const int wr = wv >> 1;    // wave row-half
    const int wc = wv & 1;     // wave col-half
    const int cm = lane & 15;  // frag m,n index
    const int q = lane >> 4;   // frag k-quarter

    // staging source
    const int sr = t >> 2;
    const int sg = (t & 3) ^ ((sr >> 1) & 3);
    const unsigned char* aS = rep + (size_t)(rb * 128 + sr) * DIM + sg * 16;
    const unsigned char* bS = rep + (size_t)(cb * 128 + sr) * DIM + sg * 16;
    unsigned char* aD = As + t * 16;  // HW-forced: wave-uniform base + lane*16
    unsigned char* bD = Bs + t * 16;

    // fragment read bases (k-invariant): row cm within 64-row group, slot q^fsw
    const int fsw = (cm >> 1) & 3;
    const unsigned char* aF = As + wr * 4096 + cm * 64 + ((q ^ fsw) << 4);
    const unsigned char* bF = Bs + wc * 4096 + cm * 64 + ((q ^ fsw) << 4);

    f32x4 acc[4][4];
#pragma unroll
    for (int i = 0; i < 4; ++i)
#pragma unroll
        for (int j = 0; j < 4; ++j) acc[i][j] = (f32x4){0.f, 0.f, 0.f, 0.f};

    for (int kk = 0; kk < DIM / 64; ++kk) {
        const unsigned char* a0 = aS + kk * 64;
        const unsigned char* b0 = bS + kk * 64;
        gld_lds16(a0, aD);                            // A rows 0..63
        gld_lds16(a0 + (size_t)64 * DIM, aD + 4096);  // A rows 64..127
        gld_lds16(b0, bD);
        gld_lds16(b0 + (size_t)64 * DIM, bD + 4096);
        __syncthreads();

        lx2 af[4], bf[4];
#pragma unroll
        for (int mi = 0; mi < 4; ++mi) af[mi] = *(const lx2*)(aF + mi * 1024);
#pragma unroll
        for (int ni = 0; ni < 4; ++ni) bf[ni] = *(const lx2*)(bF + ni * 1024);
#pragma unroll
        for (int h = 0; h < 2; ++h)
#pragma unroll
            for (int mi = 0; mi < 4; ++mi)
#pragma unroll
                for (int ni = 0; ni < 4; ++ni)
                    acc[mi][ni] = __builtin_amdgcn_mfma_f32_16x16x32_fp8_fp8(
                        af[mi][h], bf[ni][h], acc[mi][ni], 0, 0, 0);
        __syncthreads();
    }

    // Epilogue. C/D layout: col = wc*64 + ni*16 + cm, row = wr*64 + mi*16 + q*4 + reg.
    // Row-partials -> slot 2*cb+wc; transpose col-partials -> slot 2*rb+wr.
    // Row r of block i receives slots {2c,2c+1 : c>=i} ∪ {2c,2c+1 : c<i} = all 128, disjoint.
    float colsum[4];
#pragma unroll
    for (int ni = 0; ni < 4; ++ni) colsum[ni] = 0.f;

#pragma unroll
    for (int mi = 0; mi < 4; ++mi) {
#pragma unroll
        for (int reg = 0; reg < 4; ++reg) {
            const int grow = rb * 128 + wr * 64 + mi * 16 + (q << 2) + reg;
            float rs = 0.f;
#pragma unroll
            for (int ni = 0; ni < 4; ++ni) {
                const int gcol = cb * 128 + wc * 64 + ni * 16 + cm;
                const float e =
                    (grow == gcol) ? 0.f : __expf(acc[mi][ni][reg] * 2.0f);  // 1/T=2
                rs += e;
                colsum[ni] += e;
            }
            rs += __shfl_xor(rs, 1);
            rs += __shfl_xor(rs, 2);
            rs += __shfl_xor(rs, 4);
            rs += __shfl_xor(rs, 8);
            if (cm == 0) partial[(size_t)(2 * cb + wc) * NN + grow] = rs;
        }
    }

    if (rb != cb) {
#pragma unroll
        for (int ni = 0; ni < 4; ++ni) {
            colsum[ni] += __shfl_xor(colsum[ni], 16);  // fold q
            colsum[ni] += __shfl_xor(colsum[ni], 32);
        }
        if (q == 0) {
#pragma unroll
            for (int ni = 0; ni < 4; ++ni)
                partial[(size_t)(2 * rb + wr) * NN + cb * 128 + wc * 64 + ni * 16 + cm] =
                    colsum[ni];
        }
    }
}

// Kernel 3: per-row denom -> per-row loss -> 64 block sums. 2 threads/row.
__global__ void reduce_rows_kernel(const float* __restrict__ partial,
                                   const float* __restrict__ pos,
                                   float* __restrict__ bsum) {
    const int g = blockIdx.x * 256 + threadIdx.x;  // 64 x 256 = 16384
    const int r = g >> 1;
    const int half = g & 1;
    float s0 = 0.f, s1 = 0.f, s2 = 0.f, s3 = 0.f;
    for (int kb = half * 64; kb < half * 64 + 64; kb += 4) {
        s0 += partial[(size_t)(kb + 0) * NN + r];
        s1 += partial[(size_t)(kb + 1) * NN + r];
        s2 += partial[(size_t)(kb + 2) * NN + r];
        s3 += partial[(size_t)(kb + 3) * NN + r];
    }
    float s = (s0 + s1) + (s2 + s3);
    s += __shfl_xor(s, 1);  // both lanes of the pair hold the full row sum
    float v = __logf(s) - pos[r & (B_ROWS - 1)] * 2.0f;  // counted twice; *0.5 below
    v = wave_reduce_sum(v);
    __shared__ float red[4];
    const int lane = threadIdx.x & 63, wv = threadIdx.x >> 6;
    if (lane == 0) red[wv] = v;
    __syncthreads();
    if (threadIdx.x == 0)
        bsum[blockIdx.x] = (red[0] + red[1] + red[2] + red[3]) * 0.5f;
}

// Kernel 4: final scalar
__global__ void final_kernel(const float* __restrict__ bsum,
                             float* __restrict__ out) {
    float s = bsum[threadIdx.x];
    s = wave_reduce_sum(s);
    if (threadIdx.x == 0) out[0] = s * (1.0f / NN);
}

extern "C" void kernel_launch(void* const* d_in, const int* in_sizes, int n_in,
                              void* d_out, int out_size, void* d_ws, size_t ws_size,
                              hipStream_t stream) {
    const float* p1 = (const float*)d_in[0];
    const float* p2 = (const float*)d_in[1];
    char* ws = (char*)d_ws;
    unsigned char* rep = (unsigned char*)ws;                  // 8 MiB (fp8)
    float* partial = (float*)(ws + (size_t)8 * 1024 * 1024);  // 4 MiB (128 x 8192)
    float* pos = (float*)(ws + (size_t)12 * 1024 * 1024);     // 16 KiB
    float* bsum = (float*)(ws + (size_t)12 * 1024 * 1024 + 16384);  // 256 B
    float* out = (float*)d_out;

    norm_pos_kernel<<<1024, 256, 0, stream>>>(p1, p2, rep, pos);
    gemm_kernel<<<2080, 256, 0, stream>>>(rep, partial);
    reduce_rows_kernel<<<64, 256, 0, stream>>>(partial, pos, bsum);
    final_kernel<<<1, 64, 0, stream>>>(bsum, out);
}